// Round 4
// baseline (217.313 us; speedup 1.0000x reference)
//
#include <hip/hip_runtime.h>

// Joint bilateral filter 5x5, SAME zero padding.
// template: (1,3,1080,1920) f32 planar; vector: (1,2,1080,1920) f32 planar.
// out: (1,2,1080,1920) f32 (harness reads non-bf16 outputs as np.float32).
//
// Round 4: no-LDS version. Round 3 was latency-bound (VALUBusy 29%, occ 13%,
// 4.26M LDS conflict cycles). Each thread computes 4 consecutive px, reading
// its 5-row x 8-col x 5-ch window directly from global as align-4 float4s.
// Block working set ~27 KB fits L1 (32 KB/CU) -> ~7.5x L1 reuse. No barriers,
// no LDS residency cap, no bank conflicts. Taps processed dy={2,0,1,3,4} so
// center values come from the dy=2 row loads (fp order change only).

#define IMG_H 1080
#define IMG_W 1920
#define IMG_HW (IMG_H * IMG_W)
#define TS_X 64
#define TS_Y 16

typedef float f4u __attribute__((ext_vector_type(4), aligned(4)));

__device__ __forceinline__ void unpack8(float w[8], f4u a, f4u b) {
    w[0] = a.x; w[1] = a.y; w[2] = a.z; w[3] = a.w;
    w[4] = b.x; w[5] = b.y; w[6] = b.z; w[7] = b.w;
}

template <bool BORDER>
__device__ __forceinline__ void jbf_body(
    const float* __restrict__ tpl, const float* __restrict__ vec,
    int wcol0, int ybase,
    float num0[4], float num1[4], float den[4])
{
    constexpr float KVAL  = -0.125f;  // -1/(2*sigma_spatial^2)
    constexpr float SIDIV = 50.0f;    // 1/(2*sigma_intensity^2)
    const int dys[5] = {2, 0, 1, 3, 4};  // centers extracted on first iter

    float c0[4], c1[4], c2[4];

#pragma unroll
    for (int it = 0; it < 5; ++it) {
        const int dy  = dys[it];
        const int row = ybase + dy;

        float w0[8], w1[8], w2[8], wv0[8], wv1[8];

        if (!BORDER) {
            const int base = row * IMG_W + wcol0;
            const float* r0p = tpl + base;
            const float* r1p = r0p + IMG_HW;
            const float* r2p = r0p + 2 * IMG_HW;
            const float* v0p = vec + base;
            const float* v1p = v0p + IMG_HW;
            unpack8(w0,  *(const f4u*)r0p, *(const f4u*)(r0p + 4));
            unpack8(w1,  *(const f4u*)r1p, *(const f4u*)(r1p + 4));
            unpack8(w2,  *(const f4u*)r2p, *(const f4u*)(r2p + 4));
            unpack8(wv0, *(const f4u*)v0p, *(const f4u*)(v0p + 4));
            unpack8(wv1, *(const f4u*)v1p, *(const f4u*)(v1p + 4));
        } else {
            const bool rv = (row >= 0) & (row < IMG_H);
            const int  rc = row < 0 ? 0 : (row >= IMG_H ? IMG_H - 1 : row);
            const float* r0p = tpl + rc * IMG_W;
            const float* r1p = r0p + IMG_HW;
            const float* r2p = r0p + 2 * IMG_HW;
            const float* v0p = vec + rc * IMG_W;
            const float* v1p = v0p + IMG_HW;
#pragma unroll
            for (int j = 0; j < 8; ++j) {
                const int col = wcol0 + j;
                const bool cv = rv & (col >= 0) & (col < IMG_W);
                const int  cc = col < 0 ? 0 : (col >= IMG_W ? IMG_W - 1 : col);
                w0[j]  = cv ? r0p[cc] : 0.0f;
                w1[j]  = cv ? r1p[cc] : 0.0f;
                w2[j]  = cv ? r2p[cc] : 0.0f;
                wv0[j] = cv ? v0p[cc] : 0.0f;
                wv1[j] = cv ? v1p[cc] : 0.0f;
            }
        }

        if (it == 0) {  // dy == 2: center pixels are w[2..5] of this row
#pragma unroll
            for (int px = 0; px < 4; ++px) {
                c0[px] = w0[2 + px];
                c1[px] = w1[2 + px];
                c2[px] = w2[2 + px];
            }
        }

#pragma unroll
        for (int dx = 0; dx < 5; ++dx) {
#pragma unroll
            for (int px = 0; px < 4; ++px) {
                const int k = dx + px;
                const float d0 = c0[px] - w0[k];
                const float d1 = c1[px] - w1[k];
                const float d2 = c2[px] - w2[k];
                const float id = d0 * d0 + d1 * d1 + d2 * d2;
                const float t  = fabsf(KVAL - id * SIDIV);
                float coeff = 1.0f - t;
                coeff = fminf(fmaxf(coeff, 0.0f), 1.0f);
                num0[px] += wv0[k] * coeff;
                num1[px] += wv1[k] * coeff;
                den [px] += coeff;
            }
        }
    }
}

__global__ __launch_bounds__(256, 4)
void jbf_kernel(const float* __restrict__ tpl,
                const float* __restrict__ vec,
                float* __restrict__ out) {
    const int tid = threadIdx.x;
    const int tx  = tid & 15;
    const int ty  = tid >> 4;
    const int x0  = blockIdx.x * TS_X;
    const int y0  = blockIdx.y * TS_Y;

    const int gx0   = x0 + tx * 4;   // first output px col for this thread
    const int gy    = y0 + ty;       // output row
    const int wcol0 = gx0 - 2;       // col of window element 0
    const int ybase = gy - 2;        // row of dy=0

    const bool interior = (blockIdx.x >= 1) & (blockIdx.x <= 28) &
                          (blockIdx.y >= 1) & (blockIdx.y <= 66);

    float num0[4] = {0.f, 0.f, 0.f, 0.f};
    float num1[4] = {0.f, 0.f, 0.f, 0.f};
    float den [4] = {0.f, 0.f, 0.f, 0.f};

    if (interior)
        jbf_body<false>(tpl, vec, wcol0, ybase, num0, num1, den);
    else
        jbf_body<true>(tpl, vec, wcol0, ybase, num0, num1, den);

    if (gy < IMG_H) {
        float4 o0, o1;
        const float r0 = __builtin_amdgcn_rcpf(den[0]);
        const float r1 = __builtin_amdgcn_rcpf(den[1]);
        const float r2 = __builtin_amdgcn_rcpf(den[2]);
        const float r3 = __builtin_amdgcn_rcpf(den[3]);
        o0.x = num0[0] * r0; o0.y = num0[1] * r1; o0.z = num0[2] * r2; o0.w = num0[3] * r3;
        o1.x = num1[0] * r0; o1.y = num1[1] * r1; o1.z = num1[2] * r2; o1.w = num1[3] * r3;
        *(float4*)(out + (size_t)0 * IMG_HW + gy * IMG_W + gx0) = o0;
        *(float4*)(out + (size_t)1 * IMG_HW + gy * IMG_W + gx0) = o1;
    }
}

extern "C" void kernel_launch(void* const* d_in, const int* in_sizes, int n_in,
                              void* d_out, int out_size, void* d_ws, size_t ws_size,
                              hipStream_t stream) {
    const float* tpl = (const float*)d_in[0];
    const float* vec = (const float*)d_in[1];
    float* out = (float*)d_out;

    dim3 grid(IMG_W / TS_X, (IMG_H + TS_Y - 1) / TS_Y);  // 30 x 68
    jbf_kernel<<<grid, 256, 0, stream>>>(tpl, vec, out);
}

// Round 6
// 121.270 us; speedup vs baseline: 1.7920x; 1.7920x over previous
//
#include <hip/hip_runtime.h>

// Joint bilateral filter 5x5, SAME zero padding.
// template: (1,3,1080,1920) f32 planar; vector: (1,2,1080,1920) f32 planar.
// out: (1,2,1080,1920) f32 (harness reads non-bf16 outputs as np.float32).
//
// Round 6: wave-private tiles, VGPR staging (round 5's global_load_lds DMA
// faulted: halo base is (...x0-2)*4 = 8 mod 16 bytes, and the LDS-DMA path
// requires 16B-aligned global addresses; plain float4 loads at align-4 are
// proven fine). One wave per block owns a 64x8 output strip; stages its
// 12x72x5ch window via 20 float4 loads -> ds_write_b128, then computes
// 8 px/lane. __syncthreads on a 1-wave workgroup = waitcnt only, no barrier
// convoy. 17.3 KB LDS/wave -> 9 waves/CU, all independent.

#define IMG_H 1080
#define IMG_W 1920
#define IMG_HW (IMG_H * IMG_W)
#define SX 64          // strip width (output px)
#define SY 8           // strip height (output px)
#define WR 12          // window rows  = SY + 4
#define WC 72          // window cols  = SX + 8
#define CH_F (WR * WC) // 864 floats per channel
#define NF4 (CH_F / 4) // 216 float4 slots per channel
#define NCH 5

typedef float f4u __attribute__((ext_vector_type(4), aligned(4)));

__device__ __forceinline__ void loadrow(const float* sm, int off, float w[NCH][8]) {
#pragma unroll
    for (int c = 0; c < NCH; ++c) {
        const float4 a = *(const float4*)(sm + c * CH_F + off);
        const float4 b = *(const float4*)(sm + c * CH_F + off + 4);
        w[c][0] = a.x; w[c][1] = a.y; w[c][2] = a.z; w[c][3] = a.w;
        w[c][4] = b.x; w[c][5] = b.y; w[c][6] = b.z; w[c][7] = b.w;
    }
}

__device__ __forceinline__ void contrib(const float w[NCH][8], const float cen[3][4],
                                        float n0[4], float n1[4], float dn[4]) {
    constexpr float KVAL  = -0.125f;  // -1/(2*sigma_spatial^2)
    constexpr float SIDIV = 50.0f;    // 1/(2*sigma_intensity^2)
#pragma unroll
    for (int dx = 0; dx < 5; ++dx) {
#pragma unroll
        for (int px = 0; px < 4; ++px) {
            const int k = dx + px;
            const float d0 = cen[0][px] - w[0][k];
            const float d1 = cen[1][px] - w[1][k];
            const float d2 = cen[2][px] - w[2][k];
            const float id = d0 * d0 + d1 * d1 + d2 * d2;
            const float t  = fabsf(KVAL - id * SIDIV);
            float coeff = 1.0f - t;
            coeff = fminf(fmaxf(coeff, 0.0f), 1.0f);
            n0[px] += w[3][k] * coeff;
            n1[px] += w[4][k] * coeff;
            dn[px] += coeff;
        }
    }
}

__global__ __launch_bounds__(64, 2)
void jbf_kernel(const float* __restrict__ tpl,
                const float* __restrict__ vec,
                float* __restrict__ out) {
    __shared__ __align__(16) float smem[NCH * CH_F];

    const int lane = threadIdx.x;               // 0..63 (one wave per block)
    const int bx = blockIdx.x, by = blockIdx.y;
    const int x0 = bx * SX, y0 = by * SY;
    const int xs = x0 - 2, ys = y0 - 2;

    const bool interior = (bx >= 1) & (bx <= 28) & (by >= 1) & (by <= 133);

    if (interior) {
        // f4 slot j = i*64 + lane per channel; i<3 full, i==3 lanes 0..23.
        int  off[4];
        bool act[4];
#pragma unroll
        for (int i = 0; i < 4; ++i) {
            const int j = i * 64 + lane;
            act[i] = (j < NF4);
            const int jc = act[i] ? j : 0;
            const int f  = jc * 4;
            const int r  = f / WC;
            const int cc = f - r * WC;
            off[i] = r * IMG_W + cc;
        }
        const int tl = ys * IMG_W + xs;

        f4u v[NCH][4];
#pragma unroll
        for (int c = 0; c < NCH; ++c) {
            const float* __restrict__ src =
                (c < 3) ? (tpl + c * IMG_HW) : (vec + (c - 3) * IMG_HW);
#pragma unroll
            for (int i = 0; i < 4; ++i)
                if (act[i]) v[c][i] = *(const f4u*)(src + tl + off[i]);
        }
#pragma unroll
        for (int c = 0; c < NCH; ++c) {
#pragma unroll
            for (int i = 0; i < 4; ++i) {
                if (act[i]) {
                    const int j = i * 64 + lane;
                    float4 t;
                    t.x = v[c][i].x; t.y = v[c][i].y;
                    t.z = v[c][i].z; t.w = v[c][i].w;
                    *(float4*)&smem[c * CH_F + j * 4] = t;  // 16B-aligned
                }
            }
        }
    } else {
        // border: scalar bounds-checked staging with zero fill
#pragma unroll
        for (int c = 0; c < NCH; ++c) {
            const float* __restrict__ src =
                (c < 3) ? (tpl + c * IMG_HW) : (vec + (c - 3) * IMG_HW);
            for (int f = lane; f < CH_F; f += 64) {
                const int r  = f / WC;
                const int cc = f - r * WC;
                const int gy = ys + r;
                const int gx = xs + cc;
                float val = 0.0f;
                if (gy >= 0 && gy < IMG_H && gx >= 0 && gx < IMG_W)
                    val = src[gy * IMG_W + gx];
                smem[c * CH_F + f] = val;
            }
        }
    }
    __syncthreads();   // 1-wave workgroup: compiles to waitcnt only

    // ---- compute: lane owns 4 wide x 2 tall output px ----
    const int tx   = lane & 15;
    const int ty   = lane >> 4;
    const int colb = tx * 4;       // window col of first owned px - 2
    const int rb   = ty * 2;       // window row base (out row pair)

    float cenA[3][4], cenB[3][4];
    float n0[2][4] = {{0}}, n1[2][4] = {{0}}, dn[2][4] = {{0}};
    float w[NCH][8];

    // out0 (s=0) needs window rows rb+0..rb+4; out1 (s=1) rows rb+1..rb+5
    loadrow(smem, (rb + 2) * WC + colb, w);
#pragma unroll
    for (int px = 0; px < 4; ++px) {
        cenA[0][px] = w[0][2 + px]; cenA[1][px] = w[1][2 + px]; cenA[2][px] = w[2][2 + px];
    }
    contrib(w, cenA, n0[0], n1[0], dn[0]);

    loadrow(smem, (rb + 3) * WC + colb, w);
#pragma unroll
    for (int px = 0; px < 4; ++px) {
        cenB[0][px] = w[0][2 + px]; cenB[1][px] = w[1][2 + px]; cenB[2][px] = w[2][2 + px];
    }
    contrib(w, cenA, n0[0], n1[0], dn[0]);
    contrib(w, cenB, n0[1], n1[1], dn[1]);

    loadrow(smem, (rb + 2) * WC + colb, w);   // re-read row rb+2 for out1
    contrib(w, cenB, n0[1], n1[1], dn[1]);

    loadrow(smem, (rb + 0) * WC + colb, w);
    contrib(w, cenA, n0[0], n1[0], dn[0]);

    loadrow(smem, (rb + 1) * WC + colb, w);
    contrib(w, cenA, n0[0], n1[0], dn[0]);
    contrib(w, cenB, n0[1], n1[1], dn[1]);

    loadrow(smem, (rb + 4) * WC + colb, w);
    contrib(w, cenA, n0[0], n1[0], dn[0]);
    contrib(w, cenB, n0[1], n1[1], dn[1]);

    loadrow(smem, (rb + 5) * WC + colb, w);
    contrib(w, cenB, n0[1], n1[1], dn[1]);

    // ---- store: 2 rows x 2 channels, float4 each (grid covers image exactly)
    const int gx  = x0 + colb;
    const int gy0 = y0 + rb;
#pragma unroll
    for (int s = 0; s < 2; ++s) {
        const int gy = gy0 + s;
        float4 oa, ob;
        const float r0 = __builtin_amdgcn_rcpf(dn[s][0]);
        const float r1 = __builtin_amdgcn_rcpf(dn[s][1]);
        const float r2 = __builtin_amdgcn_rcpf(dn[s][2]);
        const float r3 = __builtin_amdgcn_rcpf(dn[s][3]);
        oa.x = n0[s][0] * r0; oa.y = n0[s][1] * r1; oa.z = n0[s][2] * r2; oa.w = n0[s][3] * r3;
        ob.x = n1[s][0] * r0; ob.y = n1[s][1] * r1; ob.z = n1[s][2] * r2; ob.w = n1[s][3] * r3;
        *(float4*)(out + (size_t)gy * IMG_W + gx)          = oa;
        *(float4*)(out + IMG_HW + (size_t)gy * IMG_W + gx) = ob;
    }
}

extern "C" void kernel_launch(void* const* d_in, const int* in_sizes, int n_in,
                              void* d_out, int out_size, void* d_ws, size_t ws_size,
                              hipStream_t stream) {
    const float* tpl = (const float*)d_in[0];
    const float* vec = (const float*)d_in[1];
    float* out = (float*)d_out;

    dim3 grid(IMG_W / SX, IMG_H / SY);   // 30 x 135, 64 threads = 1 wave each
    jbf_kernel<<<grid, 64, 0, stream>>>(tpl, vec, out);
}